// Round 3
// baseline (607.684 us; speedup 1.0000x reference)
//
#include <hip/hip_runtime.h>

#define NF 32
#define ED 64
#define NPAIR 496               // 32*31/2
#define VID_PER_B (NF * ED)     // 2048 floats
#define OUT_PER_B (NPAIR * ED)  // 31744 floats per batch element

// ---------------------------------------------------------------------------
// Kernel 1: vid[b] = x[b] @ W  (per-batch 32x64 @ 64x64 GEMM).
// Writes vid rows to vid + b*vstride (vstride in floats), so the same kernel
// serves both the d_ws layout (contiguous) and the out-tail stash layout.
// ---------------------------------------------------------------------------
__global__ __launch_bounds__(256, 4) void vid_gemm_kernel(
    const float* __restrict__ x, const float* __restrict__ W,
    float* __restrict__ vid, size_t vstride) {
  __shared__ float xs[NF * ED];   // 8 KB
  __shared__ float ws[ED * ED];   // 16 KB
  const int t = threadIdx.x;
  const int b = blockIdx.x;

  // Stage W: 4096 floats = 1024 float4 -> 4 per thread, coalesced.
  {
    const float4* Wg = (const float4*)W;
#pragma unroll
    for (int k = 0; k < 4; ++k) {
      int c = t + k * 256;
      *(float4*)&ws[c * 4] = Wg[c];
    }
  }
  // Stage x[b]: 2048 floats = 512 float4 -> 2 per thread, coalesced.
  {
    const float4* xg = (const float4*)(x + (size_t)b * VID_PER_B);
#pragma unroll
    for (int k = 0; k < 2; ++k) {
      int c = t + k * 256;
      *(float4*)&xs[c * 4] = xg[c];
    }
  }
  __syncthreads();

  // Per-thread tile: 2 f-rows x 4 e-cols. Same accumulation order as the
  // previously-verified kernel (absmax 0.0) -> bitwise-identical results.
  const int f0 = (t >> 4) * 2;   // 0,2,...,30
  const int e0 = (t & 15) * 4;   // 0,4,...,60
  float4 acc0 = {0.f, 0.f, 0.f, 0.f};
  float4 acc1 = {0.f, 0.f, 0.f, 0.f};
  const float* xr0 = &xs[f0 * ED];
  const float* xr1 = &xs[(f0 + 1) * ED];
#pragma unroll 8
  for (int d = 0; d < ED; ++d) {
    float a0 = xr0[d];
    float a1 = xr1[d];
    float4 w4 = *(const float4*)&ws[d * ED + e0];
    acc0.x += a0 * w4.x; acc0.y += a0 * w4.y;
    acc0.z += a0 * w4.z; acc0.w += a0 * w4.w;
    acc1.x += a1 * w4.x; acc1.y += a1 * w4.y;
    acc1.z += a1 * w4.z; acc1.w += a1 * w4.w;
  }
  float* vb = vid + (size_t)b * vstride;
  *(float4*)&vb[f0 * ED + e0] = acc0;
  *(float4*)&vb[(f0 + 1) * ED + e0] = acc1;
}

// ---------------------------------------------------------------------------
// Kernel 2: pure streaming expansion. out[b][p][e] = x[b][i][e] * vid[b][j][e].
// 18 KB LDS, one barrier, then 31 iterations of {2x ds_read_b128, 4 mul,
// 1 PLAIN global_store_dwordx4}. 8 blocks/CU resident.
// NOTE: plain stores, not nontemporal — fillBufferAligned proves plain
// full-line wave stores hit 6.27 TB/s with zero write-allocate fetch; the
// nt flag is the one difference between our store path and the fill's.
// ---------------------------------------------------------------------------
__global__ __launch_bounds__(256, 8) void expand_kernel(
    const float* __restrict__ x, const float* __restrict__ vid, size_t vstride,
    float* __restrict__ out) {
  __shared__ float xs[NF * ED];   // 8 KB
  __shared__ float vs[NF * ED];   // 8 KB
  __shared__ int ptab[NPAIR];     // ~2 KB: (i<<8)|j per pair
  const int t = threadIdx.x;
  const int b = blockIdx.x;

  // Pair table: triu_indices(32, k=1), row-major.
  for (int p = t; p < NPAIR; p += 256) {
    int i = 0, rem = p;
    while (rem >= (NF - 1 - i)) { rem -= (NF - 1 - i); ++i; }
    ptab[p] = (i << 8) | (i + 1 + rem);
  }
  // Stage x[b] and vid[b]: 512 float4 each -> 2 per thread, coalesced.
  {
    const float4* xg = (const float4*)(x + (size_t)b * VID_PER_B);
    const float4* vg = (const float4*)(vid + (size_t)b * vstride);
#pragma unroll
    for (int k = 0; k < 2; ++k) {
      int c = t + k * 256;
      *(float4*)&xs[c * 4] = xg[c];
      *(float4*)&vs[c * 4] = vg[c];
    }
  }
  __syncthreads();

  float* ob = out + (size_t)b * OUT_PER_B;
  const int g = t >> 4;          // pair-group 0..15
  const int e = (t & 15) * 4;    // e-quad 0,4,...,60
#pragma unroll 4
  for (int it = 0; it < NPAIR / 16; ++it) {   // 31 iterations
    int p = it * 16 + g;
    int pr = ptab[p];
    int i = pr >> 8, j = pr & 255;
    float4 xv = *(const float4*)&xs[i * ED + e];
    float4 vv = *(const float4*)&vs[j * ED + e];
    float4 r;
    r.x = xv.x * vv.x; r.y = xv.y * vv.y;
    r.z = xv.z * vv.z; r.w = xv.w * vv.w;
    *(float4*)&ob[(size_t)p * ED + e] = r;   // plain store (wave: 1KB contig)
  }
}

extern "C" void kernel_launch(void* const* d_in, const int* in_sizes, int n_in,
                              void* d_out, int out_size, void* d_ws, size_t ws_size,
                              hipStream_t stream) {
  const float* x = (const float*)d_in[0];
  const float* W = (const float*)d_in[1];
  float* out = (float*)d_out;
  const int B = in_sizes[0] / (NF * ED);   // 4096

  const size_t vid_bytes = (size_t)B * VID_PER_B * sizeof(float);
  float* vid;
  size_t vstride;
  if (d_ws != nullptr && ws_size >= vid_bytes) {
    // Workspace path: contiguous vid[B][32][64].
    vid = (float*)d_ws;
    vstride = VID_PER_B;
  } else {
    // Fallback: stash vid[b] in the tail 8 KB of b's own output region.
    // Kernel 2 stages it to LDS (post-barrier) before overwriting -> safe.
    vid = out + (OUT_PER_B - VID_PER_B);
    vstride = OUT_PER_B;
  }

  vid_gemm_kernel<<<B, 256, 0, stream>>>(x, W, vid, vstride);
  expand_kernel<<<B, 256, 0, stream>>>(x, vid, vstride, out);
}

// Round 4
// 534.231 us; speedup vs baseline: 1.1375x; 1.1375x over previous
//
#include <hip/hip_runtime.h>

#define NF 32
#define ED 64
#define NPAIR 496             // 32*31/2
#define XPAD 68               // padded LDS row stride (floats); 68%4==0 keeps 16B align
#define OUT_PER_B (NPAIR * ED)  // 31744 floats per batch element

typedef float f32x4 __attribute__((ext_vector_type(4)));  // clang vector: valid
                                                          // for nontemporal builtins

// Combined kernel (R0 structure, proven absmax 0.0) + nontemporal output
// stores (R2's proven -83us win: NT avoids L2 write-allocate RFO on the
// 520 MB output stream; R3 showed plain stores cost exactly that fetch).
__global__ __launch_bounds__(256, 4) void bilinear_kernel(
    const float* __restrict__ x, const float* __restrict__ W,
    float* __restrict__ out) {
  __shared__ float xs[NF * XPAD];   // x[b] rows, padded
  __shared__ float vs[NF * XPAD];   // vid[b] rows, padded
  __shared__ float ws[ED * ED];     // W row-major
  __shared__ int   ptab[NPAIR];     // (i<<8)|j per pair

  const int t = threadIdx.x;
  const int b = blockIdx.x;

  // Build pair table: triu_indices(32, k=1) in row-major order.
  for (int p = t; p < NPAIR; p += 256) {
    int i = 0, rem = p;
    while (rem >= (NF - 1 - i)) { rem -= (NF - 1 - i); ++i; }
    ptab[p] = (i << 8) | (i + 1 + rem);
  }

  // Stage W: 4096 floats = 1024 float4 -> 4 per thread, coalesced.
  {
    const float4* Wg = (const float4*)W;
#pragma unroll
    for (int k = 0; k < 4; ++k) {
      int c = t + k * 256;               // float4 index 0..1023
      float4 v = Wg[c];
      *(float4*)&ws[c * 4] = v;
    }
  }

  // Stage x[b]: 2048 floats = 512 float4 -> 2 per thread, coalesced, padded rows.
  {
    const float4* xg = (const float4*)(x + (size_t)b * (NF * ED));
#pragma unroll
    for (int k = 0; k < 2; ++k) {
      int c = t + k * 256;               // 0..511
      int f = c >> 4, d4 = c & 15;
      float4 v = xg[c];
      *(float4*)&xs[f * XPAD + d4 * 4] = v;
    }
  }
  __syncthreads();

  // In-LDS GEMM: vid = x[b] @ W. Per-thread tile: 2 f-rows x 4 e-cols.
  // Same accumulation order as the verified kernels -> bitwise-identical.
  {
    const int f0 = (t >> 4) * 2;         // 0,2,...,30
    const int e0 = (t & 15) * 4;         // 0,4,...,60
    float4 acc0 = {0.f, 0.f, 0.f, 0.f};
    float4 acc1 = {0.f, 0.f, 0.f, 0.f};
    const float* xr0 = &xs[f0 * XPAD];
    const float* xr1 = &xs[(f0 + 1) * XPAD];
#pragma unroll 8
    for (int d = 0; d < ED; ++d) {
      float a0 = xr0[d];
      float a1 = xr1[d];
      float4 w4 = *(const float4*)&ws[d * ED + e0];
      acc0.x += a0 * w4.x; acc0.y += a0 * w4.y;
      acc0.z += a0 * w4.z; acc0.w += a0 * w4.w;
      acc1.x += a1 * w4.x; acc1.y += a1 * w4.y;
      acc1.z += a1 * w4.z; acc1.w += a1 * w4.w;
    }
    *(float4*)&vs[f0 * XPAD + e0] = acc0;
    *(float4*)&vs[(f0 + 1) * XPAD + e0] = acc1;
  }
  __syncthreads();

  // Expansion: out[b][p][e] = x[b][i][e] * vid[b][j][e].
  // Wave-contiguous 1KB NT stores; output never re-read -> bypass L2
  // write-allocate (plain stores cost +520MB RFO fetch, measured R3).
  float* ob = out + (size_t)b * OUT_PER_B;
#pragma unroll 4
  for (int it = 0; it < OUT_PER_B / (256 * 4); ++it) {   // 31 iterations
    int f4 = it * 256 + t;               // float4 index within this batch's output
    int p = f4 >> 4;                     // 16 float4 per pair (64 floats)
    int e = (f4 & 15) * 4;
    int pr = ptab[p];
    int i = pr >> 8, j = pr & 255;
    f32x4 xv = *(const f32x4*)&xs[i * XPAD + e];
    f32x4 vv = *(const f32x4*)&vs[j * XPAD + e];
    f32x4 r = xv * vv;
    __builtin_nontemporal_store(r, (f32x4*)&ob[(size_t)f4 * 4]);
  }
}

extern "C" void kernel_launch(void* const* d_in, const int* in_sizes, int n_in,
                              void* d_out, int out_size, void* d_ws, size_t ws_size,
                              hipStream_t stream) {
  const float* x = (const float*)d_in[0];
  const float* W = (const float*)d_in[1];
  float* out = (float*)d_out;
  const int B = in_sizes[0] / (NF * ED);   // 4096
  bilinear_kernel<<<B, 256, 0, stream>>>(x, W, out);
}